// Round 6
// baseline (131.700 us; speedup 1.0000x reference)
//
#include <hip/hip_runtime.h>
#include <math.h>

// FedTGPClientLoss: fused CE (log-softmax gather) + prototype-MSE.
// B=16384, C=1000, D=512.
// R9 = R8 with the nontemporal-load shim fixed (builtin rejects
// HIP_vector_type*; use clang ext_vector_type(4) and bit-cast).
// Design: two kernels; rows kernel GRID-PARTITIONED into specialist blocks
// (4:1 interleaved): CE blocks stream logits (one row/wave, nontemporal) with
// only a scalar label-logit gather; MSE blocks handle 4 rows/wave with labels
// batched as one int4 and a 2-deep f/p load pipeline (protos NOT nontemporal
// so they stay L2-resident for the gather). Rationale: R6/R7 mixed a
// dependent label->proto gather chain into every wave's critical path and
// interleaved random proto segments into the burst streams; rows ran at
// ~3.4 TB/s vs 6.3 achievable (the 256MiB poison fill evicts L3 between
// iterations, so this is real HBM traffic). Math bitwise-identical to R6.

#ifndef INFINITY
#define INFINITY __builtin_inff()
#endif

typedef float float4n __attribute__((ext_vector_type(4)));

__device__ __forceinline__ float safe_exp(float dm) {
    // exp(min(dm,0)): dm <= 0 mathematically; fmin also flushes the NaN from
    // (-inf) - (-inf) on fully-padded lanes to 0 -> exp=1 paired with s=0.
    return __expf(fminf(dm, 0.0f));
}

__device__ __forceinline__ float4 ntload(const float4* p) {
    // streamed data: hint no-retention so protos keep the L2.
    // __builtin_nontemporal_load needs a native vector pointer, not
    // HIP_vector_type -- shim through ext_vector_type(4).
    const float4n v = __builtin_nontemporal_load((const float4n*)p);
    return make_float4(v.x, v.y, v.z, v.w);
}

__global__ __launch_bounds__(256) void fedtgp_rows(
    const float* __restrict__ logits,
    const int*   __restrict__ labels,
    const float* __restrict__ features,
    const float* __restrict__ protos,
    float* __restrict__ part_ce,        // [B]
    float* __restrict__ part_pl,        // [B]
    int B, int C, int D)
{
    const int tid  = threadIdx.x;
    const int lane = tid & 63;
    const int wv   = tid >> 6;
    const int C4 = C >> 2;
    const int D4 = D >> 2;

    const bool fast = (C4 >= 64 && C4 <= 256 && D4 == 128 &&
                       (C & 3) == 0 && (D & 3) == 0 && (B & 15) == 0);

    if (fast) {
        // grid = 5 * (B/16) blocks: per unit, slots 0..3 = CE, slot 4 = MSE.
        const int unit = blockIdx.x / 5;
        const int slot = blockIdx.x - unit * 5;

        if (slot < 4) {
            // ---------------- CE block: one row per wave ----------------
            const int row  = (unit * 4 + slot) * 4 + wv;
            const int lab  = labels[row];
            const float* lrow = logits + (size_t)row * C;
            const float4* l4  = (const float4*)lrow;

            const int i1 = min(lane + 64,  C4 - 1);
            const int i2 = min(lane + 128, C4 - 1);
            const int i3 = min(lane + 192, C4 - 1);

            float4 v0 = ntload(&l4[lane]);
            float4 v1 = ntload(&l4[i1]);
            float4 v2 = ntload(&l4[i2]);
            float4 v3 = ntload(&l4[i3]);
            const float ll = lrow[lab];

            const bool b1 = (lane + 64  < C4);
            const bool b2 = (lane + 128 < C4);
            const bool b3 = (lane + 192 < C4);
            const float NI = -INFINITY;
            v1.x = b1 ? v1.x : NI; v1.y = b1 ? v1.y : NI;
            v1.z = b1 ? v1.z : NI; v1.w = b1 ? v1.w : NI;
            v2.x = b2 ? v2.x : NI; v2.y = b2 ? v2.y : NI;
            v2.z = b2 ? v2.z : NI; v2.w = b2 ? v2.w : NI;
            v3.x = b3 ? v3.x : NI; v3.y = b3 ? v3.y : NI;
            v3.z = b3 ? v3.z : NI; v3.w = b3 ? v3.w : NI;

            float m = fmaxf(fmaxf(fmaxf(v0.x, v0.y), fmaxf(v0.z, v0.w)),
                            fmaxf(fmaxf(v1.x, v1.y), fmaxf(v1.z, v1.w)));
            m = fmaxf(m, fmaxf(fmaxf(v2.x, v2.y), fmaxf(v2.z, v2.w)));
            m = fmaxf(m, fmaxf(fmaxf(v3.x, v3.y), fmaxf(v3.z, v3.w)));

            float s = safe_exp(v0.x - m) + safe_exp(v0.y - m)
                    + safe_exp(v0.z - m) + safe_exp(v0.w - m);
            s += safe_exp(v1.x - m) + safe_exp(v1.y - m)
               + safe_exp(v1.z - m) + safe_exp(v1.w - m);
            s += safe_exp(v2.x - m) + safe_exp(v2.y - m)
               + safe_exp(v2.z - m) + safe_exp(v2.w - m);
            s += safe_exp(v3.x - m) + safe_exp(v3.y - m)
               + safe_exp(v3.z - m) + safe_exp(v3.w - m);

            float M = m;
            #pragma unroll
            for (int off = 32; off > 0; off >>= 1)
                M = fmaxf(M, __shfl_xor(M, off, 64));
            s *= safe_exp(m - M);
            #pragma unroll
            for (int off = 32; off > 0; off >>= 1)
                s += __shfl_xor(s, off, 64);

            if (lane == 0)
                part_ce[row] = (M + __logf(s)) - ll;
        } else {
            // ------------- MSE block: 4 rows per wave, int4 labels -------
            const int base = (unit * 4 + wv) * 4;
            const int4 lb = *(const int4*)(labels + base);
            const int l0 = lb.x, l1 = lb.y, l2 = lb.z, l3 = lb.w;

            float4 f[2][2], p[2][2];   // 2-deep buffers, literal indices only
            float q0, q1, q2, q3;

#define MISSUE(BUF, RR, LAB)                                                  \
            {                                                                 \
                const float4* f4_ = (const float4*)(features +                \
                                      (size_t)(base + (RR)) * D);             \
                const float4* p4_ = (const float4*)(protos +                  \
                                      (size_t)(LAB) * D);                     \
                f[BUF][0] = ntload(&f4_[lane]);                               \
                f[BUF][1] = ntload(&f4_[lane + 64]);                          \
                p[BUF][0] = p4_[lane];                                        \
                p[BUF][1] = p4_[lane + 64];                                   \
            }
#define MCOMP(BUF, QQ)                                                        \
            {                                                                 \
                float dx = f[BUF][0].x - p[BUF][0].x;                         \
                float dy = f[BUF][0].y - p[BUF][0].y;                         \
                float dz = f[BUF][0].z - p[BUF][0].z;                         \
                float dw = f[BUF][0].w - p[BUF][0].w;                         \
                QQ = dx*dx + dy*dy + dz*dz + dw*dw;                           \
                dx = f[BUF][1].x - p[BUF][1].x;                               \
                dy = f[BUF][1].y - p[BUF][1].y;                               \
                dz = f[BUF][1].z - p[BUF][1].z;                               \
                dw = f[BUF][1].w - p[BUF][1].w;                               \
                QQ += dx*dx + dy*dy + dz*dz + dw*dw;                          \
            }
            MISSUE(0, 0, l0);
            MISSUE(1, 1, l1);
            MCOMP(0, q0);
            MISSUE(0, 2, l2);
            MCOMP(1, q1);
            MISSUE(1, 3, l3);
            MCOMP(0, q2);
            MCOMP(1, q3);
#undef MISSUE
#undef MCOMP

            #pragma unroll
            for (int off = 32; off > 0; off >>= 1) {
                q0 += __shfl_xor(q0, off, 64);
                q1 += __shfl_xor(q1, off, 64);
                q2 += __shfl_xor(q2, off, 64);
                q3 += __shfl_xor(q3, off, 64);
            }
            if (lane == 0) {
                *(float4*)(part_pl + base) =
                    make_float4(q0 / (float)D, q1 / (float)D,
                                q2 / (float)D, q3 / (float)D);
            }
        }
    } else {
        // ---- generic fallback (correctness only; not hit for bench shape) --
        const int wave_id = blockIdx.x * 4 + wv;
        const int nwaves  = gridDim.x * 4;
        for (int row = wave_id; row < B; row += nwaves) {
            const int lab = labels[row];
            const float* lrow = logits + (size_t)row * C;
            float m = -INFINITY, s = 0.f, q = 0.f;
            for (int c = lane; c < C; c += 64) {
                const float x  = lrow[c];
                const float cm = fmaxf(m, x);
                s = s * safe_exp(m - cm) + safe_exp(x - cm);
                m = cm;
            }
            for (int d = lane; d < D; d += 64) {
                const float df = features[(size_t)row * D + d]
                               - protos[(size_t)lab * D + d];
                q += df * df;
            }
            const float ll = lrow[lab];
            #pragma unroll
            for (int off = 32; off > 0; off >>= 1) {
                const float om = __shfl_xor(m, off, 64);
                const float os = __shfl_xor(s, off, 64);
                q += __shfl_xor(q, off, 64);
                const float nm = fmaxf(m, om);
                s = s * safe_exp(m - nm) + os * safe_exp(om - nm);
                m = nm;
            }
            if (lane == 0) {
                part_ce[row] = (m + __logf(s)) - ll;
                part_pl[row] = q / (float)D;
            }
        }
    }
}

__global__ __launch_bounds__(1024) void fedtgp_finalize(
    const float* __restrict__ part_ce,
    const float* __restrict__ part_pl,
    float* __restrict__ out,
    int B, double invB)
{
    const int tid  = threadIdx.x;
    const int lane = tid & 63;
    const int wv   = tid >> 6;
    __shared__ double rc[16];
    __shared__ double rp[16];

    double c = 0.0, p = 0.0;
    for (int i = tid; i < B; i += 1024) {
        c += (double)part_ce[i];
        p += (double)part_pl[i];
    }
    #pragma unroll
    for (int off = 32; off > 0; off >>= 1) {
        c += __shfl_xor(c, off, 64);
        p += __shfl_xor(p, off, 64);
    }
    if (lane == 0) { rc[wv] = c; rp[wv] = p; }
    __syncthreads();

    if (tid == 0) {
        double cs = 0.0, ps = 0.0;
        #pragma unroll
        for (int k = 0; k < 16; ++k) { cs += rc[k]; ps += rp[k]; }
        float ce = (float)(cs * invB);
        float pl = (float)(ps * invB);
        if (!isfinite(ce)) ce = 0.0f;          // ce_loss = where(isfinite, ce, 0)
        float tot = ce + pl;                   // LAMDA = 1.0
        if (!isfinite(tot)) tot = ce;          // total = where(isfinite, total, ce)
        out[0] = tot;
        out[1] = ce;
        out[2] = pl;
    }
}

extern "C" void kernel_launch(void* const* d_in, const int* in_sizes, int n_in,
                              void* d_out, int out_size, void* d_ws, size_t ws_size,
                              hipStream_t stream)
{
    const float* logits   = (const float*)d_in[0];
    const int*   labels   = (const int*)  d_in[1];
    const float* features = (const float*)d_in[2];
    const float* protos   = (const float*)d_in[3];
    float* out = (float*)d_out;

    const int B = in_sizes[1];              // 16384
    const int C = in_sizes[0] / B;          // 1000
    const int D = in_sizes[2] / B;          // 512

    const int C4 = C >> 2;
    const int D4 = D >> 2;
    const bool fast = (C4 >= 64 && C4 <= 256 && D4 == 128 &&
                       (C & 3) == 0 && (D & 3) == 0 && (B & 15) == 0);

    float* part_ce = (float*)d_ws;          // B floats
    float* part_pl = part_ce + B;           // B floats  (total 128 KB)

    const int nb = fast ? (B / 16) * 5      // 5120 blocks: 4096 CE + 1024 MSE
                        : (B + 3) / 4;
    fedtgp_rows<<<nb, 256, 0, stream>>>(logits, labels, features, protos,
                                        part_ce, part_pl, B, C, D);
    fedtgp_finalize<<<1, 1024, 0, stream>>>(part_ce, part_pl, out, B,
                                            1.0 / (double)B);
}

// Round 7
// 119.933 us; speedup vs baseline: 1.0981x; 1.0981x over previous
//
#include <hip/hip_runtime.h>
#include <math.h>

// FedTGPClientLoss: fused CE (log-softmax gather) + prototype-MSE.
// B=16384, C=1000, D=512.
// R10 = consolidation on the proven R3/R6 structure (121.8/122.1 us).
// Ledger: R7 4-deep pipeline neutral; R9 specialist partition + nontemporal
// = -8% (nt bypassed the ~40MB/iter L3 residency R1's FETCH_SIZE proved).
// This round: (1) __launch_bounds__(256,8) pins VGPR<=64 -> 8 blocks/CU;
// (2) wave-uniform loads (labels[row], lrow[lab]) routed through
// readfirstlane -> s_load on the scalar cache, SGPR bases for proto/logit
// vector loads (saddr form); (3) per-block double2 partials (R3 style,
// consistently ~0.5us better than per-row floats) -> finalize reads 64KB
// coalesced; (4) max-butterfly -> one rescale -> sum-butterfly kept.
// Fixed floor: two 256MiB harness poison fills ~82us of the ~122 total.

#ifndef INFINITY
#define INFINITY __builtin_inff()
#endif

__device__ __forceinline__ float safe_exp(float dm) {
    // exp(min(dm,0)): dm <= 0 mathematically; fmin also flushes the NaN from
    // (-inf) - (-inf) on fully-padded lanes to 0 -> exp=1 paired with s=0.
    return __expf(fminf(dm, 0.0f));
}

__global__ __launch_bounds__(256, 8) void fedtgp_rows(
    const float* __restrict__ logits,
    const int*   __restrict__ labels,
    const float* __restrict__ features,
    const float* __restrict__ protos,
    double2* __restrict__ part,         // per-block (ce_sum, pl_sum)
    int B, int C, int D)
{
    const int tid  = threadIdx.x;
    const int lane = tid & 63;
    const int wv   = tid >> 6;
    const int row  = blockIdx.x * 4 + wv;

    __shared__ double sc[4], sp[4];

    float ce = 0.f, pl = 0.f;
    const bool valid = (row < B);

    if (valid) {
        // row is wave-uniform; pin it into an SGPR so the label and
        // label-logit gathers take the scalar-load path and the vector
        // loads get SGPR bases (saddr form).
        const int srow = __builtin_amdgcn_readfirstlane(row);
        const int lab  = labels[srow];
        const int C4 = C >> 2;
        const int D4 = D >> 2;
        const float* lrow = logits + (size_t)srow * C;

        if (C4 >= 64 && C4 <= 256 && D4 >= 64 && D4 <= 128 &&
            (C & 3) == 0 && (D & 3) == 0) {
            // ---- fast path for benchmarked shape (C=1000, D=512) ----
            const float4* l4 = (const float4*)lrow;
            const float4* f4 = (const float4*)(features + (size_t)srow * D);
            const float4* p4 = (const float4*)(protos   + (size_t)lab * D);

            const int i1 = min(lane + 64,  C4 - 1);
            const int i2 = min(lane + 128, C4 - 1);
            const int i3 = min(lane + 192, C4 - 1);
            const int j1 = min(lane + 64,  D4 - 1);

            // 8 vector loads + scalar label-logit, all independent.
            float4 v0 = l4[lane];
            float4 v1 = l4[i1];
            float4 v2 = l4[i2];
            float4 v3 = l4[i3];
            float4 f0 = f4[lane];
            float4 f1 = f4[j1];
            float4 p0 = p4[lane];
            float4 p1 = p4[j1];
            const float ll = lrow[lab];          // SGPR addr -> s_load

            const bool b1 = (lane + 64  < C4);
            const bool b2 = (lane + 128 < C4);
            const bool b3 = (lane + 192 < C4);
            const bool d1 = (lane + 64  < D4);
            const float NI = -INFINITY;
            v1.x = b1 ? v1.x : NI; v1.y = b1 ? v1.y : NI;
            v1.z = b1 ? v1.z : NI; v1.w = b1 ? v1.w : NI;
            v2.x = b2 ? v2.x : NI; v2.y = b2 ? v2.y : NI;
            v2.z = b2 ? v2.z : NI; v2.w = b2 ? v2.w : NI;
            v3.x = b3 ? v3.x : NI; v3.y = b3 ? v3.y : NI;
            v3.z = b3 ? v3.z : NI; v3.w = b3 ? v3.w : NI;

            float m = fmaxf(fmaxf(fmaxf(v0.x, v0.y), fmaxf(v0.z, v0.w)),
                            fmaxf(fmaxf(v1.x, v1.y), fmaxf(v1.z, v1.w)));
            m = fmaxf(m, fmaxf(fmaxf(v2.x, v2.y), fmaxf(v2.z, v2.w)));
            m = fmaxf(m, fmaxf(fmaxf(v3.x, v3.y), fmaxf(v3.z, v3.w)));

            float s = safe_exp(v0.x - m) + safe_exp(v0.y - m)
                    + safe_exp(v0.z - m) + safe_exp(v0.w - m);
            s += safe_exp(v1.x - m) + safe_exp(v1.y - m)
               + safe_exp(v1.z - m) + safe_exp(v1.w - m);
            s += safe_exp(v2.x - m) + safe_exp(v2.y - m)
               + safe_exp(v2.z - m) + safe_exp(v2.w - m);
            s += safe_exp(v3.x - m) + safe_exp(v3.y - m)
               + safe_exp(v3.z - m) + safe_exp(v3.w - m);

            float dx = f0.x - p0.x, dy = f0.y - p0.y;
            float dz = f0.z - p0.z, dw = f0.w - p0.w;
            float q = dx * dx + dy * dy + dz * dz + dw * dw;
            dx = f1.x - p1.x; dy = f1.y - p1.y;
            dz = f1.z - p1.z; dw = f1.w - p1.w;
            const float q1 = dx * dx + dy * dy + dz * dz + dw * dw;
            q += d1 ? q1 : 0.0f;

            // max butterfly -> one rescale exp -> (s,q) sum butterfly
            float M = m;
            #pragma unroll
            for (int off = 32; off > 0; off >>= 1)
                M = fmaxf(M, __shfl_xor(M, off, 64));
            s *= safe_exp(m - M);
            #pragma unroll
            for (int off = 32; off > 0; off >>= 1) {
                s += __shfl_xor(s, off, 64);
                q += __shfl_xor(q, off, 64);
            }

            ce = (M + __logf(s)) - ll;
            pl = q / (float)D;
        } else {
            // ---- generic fallback (correctness only; not the bench shape) --
            float m = -INFINITY, s = 0.f, q = 0.f;
            for (int c = lane; c < C; c += 64) {
                const float x  = lrow[c];
                const float cm = fmaxf(m, x);
                s = s * safe_exp(m - cm) + safe_exp(x - cm);
                m = cm;
            }
            for (int d = lane; d < D; d += 64) {
                const float df = features[(size_t)srow * D + d]
                               - protos[(size_t)lab * D + d];
                q += df * df;
            }
            const float ll = lrow[lab];
            #pragma unroll
            for (int off = 32; off > 0; off >>= 1) {
                const float om = __shfl_xor(m, off, 64);
                const float os = __shfl_xor(s, off, 64);
                q += __shfl_xor(q, off, 64);
                const float nm = fmaxf(m, om);
                s = s * safe_exp(m - nm) + os * safe_exp(om - nm);
                m = nm;
            }
            ce = (m + __logf(s)) - ll;
            pl = q / (float)D;
        }
    }

    if (lane == 0) {
        sc[wv] = valid ? (double)ce : 0.0;
        sp[wv] = valid ? (double)pl : 0.0;
    }
    __syncthreads();
    if (tid == 0)
        part[blockIdx.x] = make_double2(sc[0] + sc[1] + sc[2] + sc[3],
                                        sp[0] + sp[1] + sp[2] + sp[3]);
}

__global__ __launch_bounds__(1024) void fedtgp_finalize(
    const double2* __restrict__ part,
    float* __restrict__ out,
    int npart, double invB)
{
    const int tid  = threadIdx.x;
    const int lane = tid & 63;
    const int wv   = tid >> 6;
    __shared__ double rc[16];
    __shared__ double rp[16];

    double c = 0.0, p = 0.0;
    for (int i = tid; i < npart; i += 1024) {
        const double2 v = part[i];
        c += v.x;
        p += v.y;
    }
    #pragma unroll
    for (int off = 32; off > 0; off >>= 1) {
        c += __shfl_xor(c, off, 64);
        p += __shfl_xor(p, off, 64);
    }
    if (lane == 0) { rc[wv] = c; rp[wv] = p; }
    __syncthreads();

    if (tid == 0) {
        double cs = 0.0, ps = 0.0;
        #pragma unroll
        for (int k = 0; k < 16; ++k) { cs += rc[k]; ps += rp[k]; }
        float ce = (float)(cs * invB);
        float pl = (float)(ps * invB);
        if (!isfinite(ce)) ce = 0.0f;          // ce_loss = where(isfinite, ce, 0)
        float tot = ce + pl;                   // LAMDA = 1.0
        if (!isfinite(tot)) tot = ce;          // total = where(isfinite, total, ce)
        out[0] = tot;
        out[1] = ce;
        out[2] = pl;
    }
}

extern "C" void kernel_launch(void* const* d_in, const int* in_sizes, int n_in,
                              void* d_out, int out_size, void* d_ws, size_t ws_size,
                              hipStream_t stream)
{
    const float* logits   = (const float*)d_in[0];
    const int*   labels   = (const int*)  d_in[1];
    const float* features = (const float*)d_in[2];
    const float* protos   = (const float*)d_in[3];
    float* out = (float*)d_out;

    const int B = in_sizes[1];              // 16384
    const int C = in_sizes[0] / B;          // 1000
    const int D = in_sizes[2] / B;          // 512

    int nb = (B + 3) / 4;                   // one row per wave, 4 waves/block
    const size_t need_per_block = sizeof(double2);
    if ((size_t)nb * need_per_block > ws_size) {
        nb = (int)(ws_size / need_per_block); // degenerate-guard; never hit here
        if (nb < 1) nb = 1;
    }

    double2* part = (double2*)d_ws;         // nb * 16 B = 64 KB << ws_size

    fedtgp_rows<<<nb, 256, 0, stream>>>(logits, labels, features, protos,
                                        part, B, C, D);
    fedtgp_finalize<<<1, 1024, 0, stream>>>(part, out, nb, 1.0 / (double)B);
}